// Round 5
// baseline (264.274 us; speedup 1.0000x reference)
//
#include <hip/hip_runtime.h>
#include <hip/hip_bf16.h>
#include <math.h>

// Problem constants (fixed by setup_inputs)
#define NN   5570
#define BB   16
#define CIN  35
#define NJ   16        // (d,j): d in [0,4), j in [0,4) (j: gate-o2, gate-o3, upd-o0, upd-o1)
#define MPAD 5632      // NN padded to 88*64
#define NCHUNK 176     // MPAD/32
#define OUTER 4        // split-K slices (blockIdx.z)
#define KW   1408      // MPAD/OUTER, 44 steps of 32

// workspace layout (float offsets); total ~5.8 MB
#define OFF_PG   0                         // [BB][NN][4] fp32 (atomic accum) = 356480
#define OFF_RSUM 356480                    // [MPAD] fp32 (atomic accum)
#define OFF_G0C  362112                    // [BB][NN][4] fp32 = 356480
#define OFF_GTF  718592                    // gtf bf16 [NCHUNK][BB][64][8]
#define ZERO_BYTES ((356480 + 5632) * 4)   // pg + rsum

typedef __attribute__((ext_vector_type(8))) short  short8;
typedef __attribute__((ext_vector_type(4))) float  floatx4;

static __device__ inline ushort f2bf(float f) {
    union { __hip_bfloat16 h; ushort u; } cv;
    cv.h = __float2bfloat16(f);
    return cv.u;
}

// ---------------------------------------------------------------------------
// Kernel G: per (b, m):
//   a0[dj] = sum_c x[b,m,c] * w_k0[d,c,j];  g0c[b][m][j] = sum_d E[m,d]*a0[dj]
//   a1[dj] = sum_c x[b,m,c] * w_k1[d,c,j] -> gtf bf16, MFMA-B-fragment order:
//       gtf[((chunk*16 + b)*64 + quad*16 + dj)*8 + u], chunk=m>>5, quad=(m>>3)&3, u=m&7
// tail m in [NN, MPAD): gtf <- 0
// ---------------------------------------------------------------------------
__global__ __launch_bounds__(256)
void kg_g(const float* __restrict__ x, const float* __restrict__ e,
          const float* __restrict__ wg, const float* __restrict__ wu,
          float* __restrict__ g0c, ushort* __restrict__ gtf) {
    __shared__ float xs[256 * CIN];
    __shared__ float wl[8 * CIN * 4];   // [(k*4+d)*35 + c]*4 + j
    int tid = threadIdx.x;
    int b   = blockIdx.y;
    int m0  = blockIdx.x * 256;

    for (int i = tid; i < 8 * CIN * 4; i += 256) {
        int j = i & 3, rest = i >> 2;
        int c = rest % CIN, kd = rest / CIN;
        int k = kd >> 2, d = kd & 3;
        float v;
        if (j < 2) v = wg[((d * 2 + k) * 37 + c) * 4 + 2 + j];
        else       v = wu[((d * 2 + k) * 37 + c) * 2 + (j - 2)];
        wl[i] = v;
    }
    int rows = NN - m0; if (rows > 256) rows = 256; if (rows < 0) rows = 0;
    const float* xsrc = x + ((size_t)b * NN + m0) * CIN;
    for (int i = tid; i < rows * CIN; i += 256) xs[i] = xsrc[i];
    __syncthreads();

    int m = m0 + tid;
    const int chunk = m >> 5, quad = (m >> 3) & 3, u = m & 7;
    ushort* gdst = gtf + (((size_t)chunk * 16 + b) * 64 + quad * 16) * 8 + u;

    if (m < NN) {
        float a0[16], a1[16];
        #pragma unroll
        for (int i = 0; i < 16; ++i) { a0[i] = 0.f; a1[i] = 0.f; }
        for (int c = 0; c < CIN; ++c) {
            float xa = xs[tid * CIN + c];
            #pragma unroll
            for (int kd = 0; kd < 8; ++kd) {
                const float4 w = *(const float4*)&wl[(kd * CIN + c) * 4];
                const int d4 = (kd & 3) * 4;
                if (kd < 4) {
                    a0[d4+0] += xa*w.x; a0[d4+1] += xa*w.y;
                    a0[d4+2] += xa*w.z; a0[d4+3] += xa*w.w;
                } else {
                    a1[d4+0] += xa*w.x; a1[d4+1] += xa*w.y;
                    a1[d4+2] += xa*w.z; a1[d4+3] += xa*w.w;
                }
            }
        }
        // fold E-contraction for k=0 term: p0[j] = sum_d E[m,d]*a0[d*4+j]
        float4 em4 = ((const float4*)e)[m];
        float ed[4] = {em4.x, em4.y, em4.z, em4.w};
        float p0[4];
        #pragma unroll
        for (int j = 0; j < 4; ++j) {
            p0[j] = ed[0]*a0[j] + ed[1]*a0[4+j] + ed[2]*a0[8+j] + ed[3]*a0[12+j];
        }
        ((float4*)g0c)[(size_t)b * NN + m] = make_float4(p0[0], p0[1], p0[2], p0[3]);
        #pragma unroll
        for (int dj = 0; dj < 16; ++dj)
            gdst[(size_t)dj * 8] = f2bf(a1[dj]);
    } else {
        #pragma unroll
        for (int dj = 0; dj < 16; ++dj)
            gdst[(size_t)dj * 8] = 0;
    }
}

// ---------------------------------------------------------------------------
// Kernel B (MFMA, barrier-free, zero LDS, low-acc/high-occupancy):
// Wave w owns rows n0 = bx*64 + w*16 and 4 col-tiles ct = ctg*4..ctg*4+3.
// A-fragment scores in-register (lane holds A[n0+l15][quad*8+u]).
// Epilogue: contract with E[n,d] across dj lanes via per-lane atomicAdd into
// pg[b][n][jj] (fp32); rsum via atomicAdd (only ctg==0 waves compute it).
// ---------------------------------------------------------------------------
template <bool CHECK, bool RS>
static __device__ inline void kb_body(const float4* __restrict__ E4,
                                      const ushort* __restrict__ gl,
                                      const float4 en, int k0,
                                      floatx4 (&acc)[4], float& rowsum,
                                      int quad) {
    #pragma unroll 4
    for (int step = 0; step < KW / 32; ++step) {
        const int mq = k0 + step * 32 + quad * 8;
        short8 afrag;
        #pragma unroll
        for (int u = 0; u < 8; ++u) {
            int m = mq + u;
            float4 em = E4[(CHECK && m >= NN) ? 0 : m];
            float dt = en.x*em.x + en.y*em.y + en.z*em.z + en.w*em.w;
            float sv = __expf(fmaxf(dt, 0.f));
            if (CHECK && m >= NN) sv = 0.f;
            if (RS) rowsum += sv;
            afrag[u] = (short)f2bf(sv);
        }
        const ushort* gs = gl + ((size_t)((k0 >> 5) + step) << 13);
        #pragma unroll
        for (int c = 0; c < 4; ++c) {
            short8 bf = *(const short8*)&gs[c * 512];
            acc[c] = __builtin_amdgcn_mfma_f32_16x16x32_bf16(afrag, bf, acc[c], 0, 0, 0);
        }
    }
}

__global__ __launch_bounds__(256, 8)
void kb_pg(const float* __restrict__ e, const ushort* __restrict__ gtf,
           float* __restrict__ pg, float* __restrict__ rsum) {
    const int tid  = threadIdx.x;
    const int wave = tid >> 6;
    const int lane = tid & 63;
    const int l15  = lane & 15;
    const int quad = lane >> 4;
    const int n0   = blockIdx.x * 64 + wave * 16;
    const int ctg  = blockIdx.y;
    const int s    = blockIdx.z;
    const int k0   = s * KW;
    const float4* E4 = (const float4*)e;

    const int nr = n0 + l15;
    const float4 en = E4[nr < NN ? nr : 0];

    floatx4 acc[4];
    #pragma unroll
    for (int i = 0; i < 4; ++i) acc[i] = (floatx4){0.f, 0.f, 0.f, 0.f};
    float rowsum = 0.f;

    const ushort* gl = gtf + (size_t)ctg * 2048 + (size_t)lane * 8;

    const bool tail = (k0 + KW > NN);
    if (ctg == 0) {
        if (tail) kb_body<true , true >(E4, gl, en, k0, acc, rowsum, quad);
        else      kb_body<false, true >(E4, gl, en, k0, acc, rowsum, quad);
    } else {
        if (tail) kb_body<true , false>(E4, gl, en, k0, acc, rowsum, quad);
        else      kb_body<false, false>(E4, gl, en, k0, acc, rowsum, quad);
    }

    // rsum: rowsum for row l15 is split across quads -> butterfly, quad0 stores
    if (ctg == 0) {
        rowsum += __shfl_xor(rowsum, 16);
        rowsum += __shfl_xor(rowsum, 32);
        if (quad == 0 && nr < NN) atomicAdd(&rsum[nr], rowsum);
    }

    // epilogue: acc[c][j] = D[n = n0+quad*4+j][dj = l15], ct = ctg*4+c
    // pg[ct][n][jj = l15&3] += E[n][d = l15>>2] * acc
    const int dsel = l15 >> 2, jj = l15 & 3;
    float end[4];
    #pragma unroll
    for (int j = 0; j < 4; ++j) {
        int n = n0 + quad * 4 + j;
        end[j] = (n < NN) ? e[n * 4 + dsel] : 0.f;
    }
    #pragma unroll
    for (int c = 0; c < 4; ++c) {
        const int ct = ctg * 4 + c;
        #pragma unroll
        for (int j = 0; j < 4; ++j) {
            int n = n0 + quad * 4 + j;
            if (n < NN)
                atomicAdd(&pg[((size_t)ct * NN + n) * 4 + jj], end[j] * acc[c][j]);
        }
    }
}

// ---------------------------------------------------------------------------
// Kernel E: tiny epilogue
// pre[j] = g0c[b][n][j] + (1/rsum[n]) * pg[b][n][j] + sum_d E[n,d]*bias[d][j]
// R=sigmoid(pre[0..1]), C=tanh(pre[2..3]), h=(1-R)*C, y = relu(h)@lin_w + lin_b
// ---------------------------------------------------------------------------
static __device__ inline float fsig(float x) {
    return 1.f / (1.f + __expf(-x));
}
static __device__ inline float ftanh(float x) {
    float t = __expf(fminf(2.f * x, 80.f));
    return (t - 1.f) / (t + 1.f);
}

__global__ __launch_bounds__(256)
void ke_out(const float* __restrict__ e, const float* __restrict__ rsum,
            const float* __restrict__ g0c, const float* __restrict__ pg,
            const float* __restrict__ bg, const float* __restrict__ bu,
            const float* __restrict__ lw, const float* __restrict__ lb,
            float* __restrict__ out) {
    int n = blockIdx.x * 256 + threadIdx.x;
    int b = blockIdx.y;
    if (n >= NN) return;
    float4 ev = ((const float4*)e)[n];
    float ed[4] = {ev.x, ev.y, ev.z, ev.w};
    float rd = 1.f / rsum[n];
    float4 g0v = ((const float4*)g0c)[(size_t)b * NN + n];
    float4 pgv = ((const float4*)pg)[(size_t)b * NN + n];
    float g0f[4] = {g0v.x, g0v.y, g0v.z, g0v.w};
    float pgf[4] = {pgv.x, pgv.y, pgv.z, pgv.w};

    float pre[4];
    #pragma unroll
    for (int j = 0; j < 4; ++j) {
        float bj = 0.f;
        #pragma unroll
        for (int d = 0; d < 4; ++d) {
            float bp = (j < 2) ? bg[d * 4 + 2 + j] : bu[d * 2 + (j - 2)];
            bj += ed[d] * bp;
        }
        pre[j] = g0f[j] + rd * pgf[j] + bj;
    }
    float R0 = fsig(pre[0]);
    float R1 = fsig(pre[1]);
    float C0 = ftanh(pre[2]);
    float C1 = ftanh(pre[3]);
    float h0 = (1.f - R0) * C0;
    float h1 = (1.f - R1) * C1;
    float y = fmaxf(h0, 0.f) * lw[0] + fmaxf(h1, 0.f) * lw[1] + lb[0];
    out[(size_t)b * NN + n] = y;
}

// ---------------------------------------------------------------------------
extern "C" void kernel_launch(void* const* d_in, const int* in_sizes, int n_in,
                              void* d_out, int out_size, void* d_ws, size_t ws_size,
                              hipStream_t stream) {
    const float* x  = (const float*)d_in[0];
    const float* e  = (const float*)d_in[1];
    const float* wg = (const float*)d_in[2];
    const float* bg = (const float*)d_in[3];
    const float* wu = (const float*)d_in[4];
    const float* bu = (const float*)d_in[5];
    const float* lw = (const float*)d_in[6];
    const float* lb = (const float*)d_in[7];
    float* out = (float*)d_out;

    float*  wsf  = (float*)d_ws;
    float*  pg   = wsf + OFF_PG;
    float*  rsum = wsf + OFF_RSUM;
    float*  g0c  = wsf + OFF_G0C;
    ushort* gtf  = (ushort*)(wsf + OFF_GTF);

    hipMemsetAsync(d_ws, 0, ZERO_BYTES, stream);  // zero pg + rsum accumulators
    hipLaunchKernelGGL(kg_g, dim3(22, 16), dim3(256), 0, stream, x, e, wg, wu, g0c, gtf);
    hipLaunchKernelGGL(kb_pg, dim3(MPAD / 64, 4, OUTER), dim3(256), 0, stream,
                       e, gtf, pg, rsum);
    hipLaunchKernelGGL(ke_out, dim3(22, 16), dim3(256), 0, stream,
                       e, rsum, g0c, pg, bg, bu, lw, lb, out);
}

// Round 6
// 195.165 us; speedup vs baseline: 1.3541x; 1.3541x over previous
//
#include <hip/hip_runtime.h>
#include <hip/hip_bf16.h>
#include <math.h>

// Problem constants (fixed by setup_inputs)
#define NN   5570
#define BB   16
#define CIN  35
#define MPAD 5632      // NN padded to 88*64
#define NCHUNK 176     // MPAD/32  (k-chunks of 32)
#define NRT  352       // MPAD/16  (row tiles)
#define OUTER 11       // split-K slices; 16 chunks each
#define CPS  16        // chunks per slice

// workspace layout (float offsets); total 20,920,320 floats = 83.7 MB
#define OFF_RSUM 0                          // [OUTER][MPAD] fp32 = 61952
#define OFF_G0C  61952                      // [BB][NN][4] fp32 = 356480
#define OFF_PGP  418432                     // [OUTER][BB][NN][4] fp32 = 3921280
#define OFF_GTF  4339712                    // gtf bf16 [NCHUNK][BB][64][8] = 720896 fl
#define OFF_SF   5060608                    // sf  bf16 [NRT][NCHUNK][512]  = 15859712 fl

typedef __attribute__((ext_vector_type(8))) short  short8;
typedef __attribute__((ext_vector_type(4))) float  floatx4;

static __device__ inline ushort f2bf(float f) {
    union { __hip_bfloat16 h; ushort u; } cv;
    cv.h = __float2bfloat16(f);
    return cv.u;
}

// ---------------------------------------------------------------------------
// Kernel G: per (b, m):
//   a0[dj] = sum_c x[b,m,c]*w_k0[d,c,j];  g0c[b][m][j] = sum_d E[m,d]*a0[dj]
//   a1[dj] = sum_c x[b,m,c]*w_k1[d,c,j] -> gtf bf16 in MFMA-B-fragment order:
//       gtf[((ck*16 + b)*64 + quad*16 + dj)*8 + u],  m = ck*32 + quad*8 + u
// Writes go through an LDS transpose so global stores are coalesced short8.
// ---------------------------------------------------------------------------
__global__ __launch_bounds__(256)
void kg_g(const float* __restrict__ x, const float* __restrict__ e,
          const float* __restrict__ wg, const float* __restrict__ wu,
          float* __restrict__ g0c, ushort* __restrict__ gtf) {
    __shared__ float xs[256 * CIN];
    __shared__ float wl[8 * CIN * 4];    // [(k*4+d)*35 + c]*4 + j
    __shared__ ushort ls[256 * 17];      // staged a1, row stride 17 (pad)
    int tid = threadIdx.x;
    int b   = blockIdx.y;
    int m0  = blockIdx.x * 256;

    for (int i = tid; i < 8 * CIN * 4; i += 256) {
        int j = i & 3, rest = i >> 2;
        int c = rest % CIN, kd = rest / CIN;
        int k = kd >> 2, d = kd & 3;
        float v;
        if (j < 2) v = wg[((d * 2 + k) * 37 + c) * 4 + 2 + j];
        else       v = wu[((d * 2 + k) * 37 + c) * 2 + (j - 2)];
        wl[i] = v;
    }
    int rows = NN - m0; if (rows > 256) rows = 256; if (rows < 0) rows = 0;
    const float* xsrc = x + ((size_t)b * NN + m0) * CIN;
    for (int i = tid; i < rows * CIN; i += 256) xs[i] = xsrc[i];
    __syncthreads();

    int m = m0 + tid;
    float a1[16];
    #pragma unroll
    for (int i = 0; i < 16; ++i) a1[i] = 0.f;

    if (m < NN) {
        float a0[16];
        #pragma unroll
        for (int i = 0; i < 16; ++i) a0[i] = 0.f;
        for (int c = 0; c < CIN; ++c) {
            float xa = xs[tid * CIN + c];
            #pragma unroll
            for (int kd = 0; kd < 8; ++kd) {
                const float4 w = *(const float4*)&wl[(kd * CIN + c) * 4];
                const int d4 = (kd & 3) * 4;
                if (kd < 4) {
                    a0[d4+0] += xa*w.x; a0[d4+1] += xa*w.y;
                    a0[d4+2] += xa*w.z; a0[d4+3] += xa*w.w;
                } else {
                    a1[d4+0] += xa*w.x; a1[d4+1] += xa*w.y;
                    a1[d4+2] += xa*w.z; a1[d4+3] += xa*w.w;
                }
            }
        }
        // fold E-contraction for k=0 term: p0[j] = sum_d E[m,d]*a0[d*4+j]
        float4 em4 = ((const float4*)e)[m];
        float p0[4];
        #pragma unroll
        for (int j = 0; j < 4; ++j)
            p0[j] = em4.x*a0[j] + em4.y*a0[4+j] + em4.z*a0[8+j] + em4.w*a0[12+j];
        ((float4*)g0c)[(size_t)b * NN + m] = make_float4(p0[0], p0[1], p0[2], p0[3]);
    }

    // stage a1 -> LDS [m_local][dj] (stride 17)
    #pragma unroll
    for (int dj = 0; dj < 16; ++dj) ls[tid * 17 + dj] = f2bf(a1[dj]);
    __syncthreads();

    // coalesced write-out: wave w handles local chunks {2w, 2w+1}
    const int wave = tid >> 6, lane = tid & 63;
    const int qo = lane >> 4, dj = lane & 15;
    #pragma unroll
    for (int i = 0; i < 2; ++i) {
        const int lc = wave * 2 + i;
        const int ck = blockIdx.x * 8 + lc;
        short8 v;
        #pragma unroll
        for (int u = 0; u < 8; ++u)
            v[u] = (short)ls[(lc * 32 + qo * 8 + u) * 17 + dj];
        *(short8*)&gtf[((size_t)(ck * 16 + b)) * 512 + lane * 8] = v;
    }
}

// ---------------------------------------------------------------------------
// Kernel S: scores in MFMA A-fragment order + per-slice row sums.
//   sf[rt][ck][lane*8+u] = bf16( exp(relu(E[rt*16+l15] . E[ck*32+quad*8+u])) )
//   rsums[s][n] = sum over slice's m of the fp32 scores (row n)
// Wave owns one row-tile rt and 16 chunks (slice s). No LDS, no barriers.
// ---------------------------------------------------------------------------
template <bool CHECK>
static __device__ inline void ks_body(const float4* __restrict__ E4,
                                      ushort* __restrict__ sfw,
                                      const float4 en, int ck0,
                                      float& rowsum, int quad) {
    #pragma unroll 4
    for (int st = 0; st < CPS; ++st) {
        const int mq = (ck0 + st) * 32 + quad * 8;
        short8 a;
        #pragma unroll
        for (int u = 0; u < 8; ++u) {
            int m = mq + u;
            float4 em = E4[(CHECK && m >= NN) ? 0 : m];
            float dt = en.x*em.x + en.y*em.y + en.z*em.z + en.w*em.w;
            float sv = __expf(fmaxf(dt, 0.f));
            if (CHECK && m >= NN) sv = 0.f;
            rowsum += sv;
            a[u] = (short)f2bf(sv);
        }
        *(short8*)(sfw + (size_t)st * 512) = a;
    }
}

__global__ __launch_bounds__(256)
void ks_score(const float* __restrict__ e, ushort* __restrict__ sf,
              float* __restrict__ rsums) {
    const int tid  = threadIdx.x;
    const int wave = tid >> 6;
    const int lane = tid & 63;
    const int l15  = lane & 15;
    const int quad = lane >> 4;
    const int rt   = blockIdx.x * 4 + wave;
    const int s    = blockIdx.y;
    const int ck0  = s * CPS;
    const float4* E4 = (const float4*)e;

    const int nr = rt * 16 + l15;
    const float4 en = E4[nr < NN ? nr : 0];

    ushort* sfw = sf + ((size_t)rt * NCHUNK + ck0) * 512 + lane * 8;
    float rowsum = 0.f;

    if ((ck0 + CPS) * 32 <= NN) ks_body<false>(E4, sfw, en, ck0, rowsum, quad);
    else                        ks_body<true >(E4, sfw, en, ck0, rowsum, quad);

    rowsum += __shfl_xor(rowsum, 16);
    rowsum += __shfl_xor(rowsum, 32);
    if (quad == 0) rsums[(size_t)s * MPAD + nr] = rowsum;   // nr < MPAD always
}

// ---------------------------------------------------------------------------
// Kernel B: pure streaming fragment GEMM + fused E-contraction epilogue.
// Wave: row-tile rt, all 16 col-tiles (ct == batch), k-slice s (16 chunks).
// Per step: 1 coalesced A-frag (1KB/wave) + 16 L2-hot B-frags + 16 MFMA.
// Epilogue: val = acc*E[n, l15>>2]; reduce over d via shfl_xor(4),(8);
// lanes l15<4 store fp32 partial pgp[s][ct][n][jj].
// ---------------------------------------------------------------------------
__global__ __launch_bounds__(256)
void kb_pg(const float* __restrict__ e, const ushort* __restrict__ sf,
           const ushort* __restrict__ gtf, float* __restrict__ pgp) {
    const int tid  = threadIdx.x;
    const int wave = tid >> 6;
    const int lane = tid & 63;
    const int l15  = lane & 15;
    const int quad = lane >> 4;
    const int rt   = blockIdx.x * 4 + wave;
    const int s    = blockIdx.y;
    const int ck0  = s * CPS;

    floatx4 acc[16];
    #pragma unroll
    for (int i = 0; i < 16; ++i) acc[i] = (floatx4){0.f, 0.f, 0.f, 0.f};

    const ushort* sfw = sf + ((size_t)rt * NCHUNK + ck0) * 512 + lane * 8;
    const ushort* gl  = gtf + (size_t)ck0 * 8192 + lane * 8;

    #pragma unroll 2
    for (int st = 0; st < CPS; ++st) {
        short8 af = *(const short8*)(sfw + (size_t)st * 512);
        const ushort* gs = gl + (size_t)st * 8192;
        #pragma unroll
        for (int ct = 0; ct < 16; ++ct) {
            short8 bf = *(const short8*)&gs[ct * 512];
            acc[ct] = __builtin_amdgcn_mfma_f32_16x16x32_bf16(af, bf, acc[ct], 0, 0, 0);
        }
    }

    // epilogue: contract dj = d*4+jj (= l15) with E[n,d], reduce over d
    const int dsel = l15 >> 2, jj = l15 & 3;
    float end[4];
    #pragma unroll
    for (int j = 0; j < 4; ++j) {
        int n = rt * 16 + quad * 4 + j;
        end[j] = (n < NN) ? e[n * 4 + dsel] : 0.f;
    }
    #pragma unroll
    for (int ct = 0; ct < 16; ++ct) {
        #pragma unroll
        for (int j = 0; j < 4; ++j) {
            float v = end[j] * acc[ct][j];
            v += __shfl_xor(v, 4);
            v += __shfl_xor(v, 8);
            int n = rt * 16 + quad * 4 + j;
            if (l15 < 4 && n < NN)
                pgp[(((size_t)s * BB + ct) * NN + n) * 4 + jj] = v;
        }
    }
}

// ---------------------------------------------------------------------------
// Kernel E: tiny epilogue
// pre[j] = g0c[b][n][j] + (1/sum_s rsums[s][n]) * sum_s pgp[s][b][n][j]
//          + sum_d E[n,d]*bias[d][j]
// R=sigmoid(pre[0..1]), C=tanh(pre[2..3]), h=(1-R)*C, y = relu(h)@lin_w + lin_b
// ---------------------------------------------------------------------------
static __device__ inline float fsig(float x) {
    return 1.f / (1.f + __expf(-x));
}
static __device__ inline float ftanh(float x) {
    float t = __expf(fminf(2.f * x, 80.f));
    return (t - 1.f) / (t + 1.f);
}

__global__ __launch_bounds__(256)
void ke_out(const float* __restrict__ e, const float* __restrict__ rsums,
            const float* __restrict__ g0c, const float* __restrict__ pgp,
            const float* __restrict__ bg, const float* __restrict__ bu,
            const float* __restrict__ lw, const float* __restrict__ lb,
            float* __restrict__ out) {
    int n = blockIdx.x * 256 + threadIdx.x;
    int b = blockIdx.y;
    if (n >= NN) return;
    float4 ev = ((const float4*)e)[n];
    float ed[4] = {ev.x, ev.y, ev.z, ev.w};
    float den = 0.f;
    #pragma unroll
    for (int s = 0; s < OUTER; ++s) den += rsums[(size_t)s * MPAD + n];
    float rd = 1.f / den;

    float pgf[4] = {0.f, 0.f, 0.f, 0.f};
    #pragma unroll
    for (int s = 0; s < OUTER; ++s) {
        float4 t = ((const float4*)pgp)[((size_t)s * BB + b) * NN + n];
        pgf[0] += t.x; pgf[1] += t.y; pgf[2] += t.z; pgf[3] += t.w;
    }
    float4 g0v = ((const float4*)g0c)[(size_t)b * NN + n];
    float g0f[4] = {g0v.x, g0v.y, g0v.z, g0v.w};

    float pre[4];
    #pragma unroll
    for (int j = 0; j < 4; ++j) {
        float bj = 0.f;
        #pragma unroll
        for (int d = 0; d < 4; ++d) {
            float bp = (j < 2) ? bg[d * 4 + 2 + j] : bu[d * 2 + (j - 2)];
            bj += ed[d] * bp;
        }
        pre[j] = g0f[j] + rd * pgf[j] + bj;
    }
    float R0 = fsig(pre[0]);
    float R1 = fsig(pre[1]);
    float C0 = ftanh(pre[2]);
    float C1 = ftanh(pre[3]);
    float h0 = (1.f - R0) * C0;
    float h1 = (1.f - R1) * C1;
    float y = fmaxf(h0, 0.f) * lw[0] + fmaxf(h1, 0.f) * lw[1] + lb[0];
    out[(size_t)b * NN + n] = y;
}

// ---------------------------------------------------------------------------
extern "C" void kernel_launch(void* const* d_in, const int* in_sizes, int n_in,
                              void* d_out, int out_size, void* d_ws, size_t ws_size,
                              hipStream_t stream) {
    const float* x  = (const float*)d_in[0];
    const float* e  = (const float*)d_in[1];
    const float* wg = (const float*)d_in[2];
    const float* bg = (const float*)d_in[3];
    const float* wu = (const float*)d_in[4];
    const float* bu = (const float*)d_in[5];
    const float* lw = (const float*)d_in[6];
    const float* lb = (const float*)d_in[7];
    float* out = (float*)d_out;

    float*  wsf   = (float*)d_ws;
    float*  rsums = wsf + OFF_RSUM;
    float*  g0c   = wsf + OFF_G0C;
    float*  pgp   = wsf + OFF_PGP;
    ushort* gtf   = (ushort*)(wsf + OFF_GTF);
    ushort* sf    = (ushort*)(wsf + OFF_SF);

    hipLaunchKernelGGL(kg_g, dim3(22, 16), dim3(256), 0, stream, x, e, wg, wu, g0c, gtf);
    hipLaunchKernelGGL(ks_score, dim3(88, OUTER), dim3(256), 0, stream, e, sf, rsums);
    hipLaunchKernelGGL(kb_pg, dim3(88, OUTER), dim3(256), 0, stream, e, sf, gtf, pgp);
    hipLaunchKernelGGL(ke_out, dim3(22, 16), dim3(256), 0, stream,
                       e, rsums, g0c, pgp, bg, bu, lw, lb, out);
}

// Round 7
// 164.028 us; speedup vs baseline: 1.6112x; 1.1898x over previous
//
#include <hip/hip_runtime.h>
#include <hip/hip_bf16.h>
#include <math.h>

// Problem constants (fixed by setup_inputs)
#define NN   5570
#define BB   16
#define CIN  35
#define MPAD 5632      // NN padded to 88*64
#define NCHUNK 176     // MPAD/32  (k-chunks of 32)
#define OUTER 11       // split-K slices (blockIdx.y); 16 chunks = 512 k each
#define CPS  16        // chunks per slice

// workspace layout (float offsets); total 5,060,608 floats ~= 20.2 MB
#define OFF_RSUM 0                          // [OUTER][MPAD] fp32 = 61952
#define OFF_G0C  61952                      // [BB][NN][4] fp32 = 356480
#define OFF_PGP  418432                     // [OUTER][BB][NN][4] fp32 = 3921280
#define OFF_GTF  4339712                    // gtf bf16 [NCHUNK][BB][64][8]

typedef __attribute__((ext_vector_type(8))) short  short8;
typedef __attribute__((ext_vector_type(4))) float  floatx4;

static __device__ inline ushort f2bf(float f) {
    union { __hip_bfloat16 h; ushort u; } cv;
    cv.h = __float2bfloat16(f);
    return cv.u;
}

// ---------------------------------------------------------------------------
// Kernel G: per (b, m):
//   a0[dj] = sum_c x[b,m,c]*w_k0[d,c,j];  g0c[b][m][j] = sum_d E[m,d]*a0[dj]
//   a1[dj] = sum_c x[b,m,c]*w_k1[d,c,j] -> gtf bf16 in MFMA-B-fragment order:
//       gtf[((ck*16 + b)*64 + quad*16 + dj)*8 + u],  m = ck*32 + quad*8 + u
// Writes go through an LDS transpose so global stores are coalesced short8.
// ---------------------------------------------------------------------------
__global__ __launch_bounds__(256)
void kg_g(const float* __restrict__ x, const float* __restrict__ e,
          const float* __restrict__ wg, const float* __restrict__ wu,
          float* __restrict__ g0c, ushort* __restrict__ gtf) {
    __shared__ float xs[256 * CIN];
    __shared__ float wl[8 * CIN * 4];    // [(k*4+d)*35 + c]*4 + j
    __shared__ ushort ls[256 * 17];      // staged a1, row stride 17 (pad)
    int tid = threadIdx.x;
    int b   = blockIdx.y;
    int m0  = blockIdx.x * 256;

    for (int i = tid; i < 8 * CIN * 4; i += 256) {
        int j = i & 3, rest = i >> 2;
        int c = rest % CIN, kd = rest / CIN;
        int k = kd >> 2, d = kd & 3;
        float v;
        if (j < 2) v = wg[((d * 2 + k) * 37 + c) * 4 + 2 + j];
        else       v = wu[((d * 2 + k) * 37 + c) * 2 + (j - 2)];
        wl[i] = v;
    }
    int rows = NN - m0; if (rows > 256) rows = 256; if (rows < 0) rows = 0;
    const float* xsrc = x + ((size_t)b * NN + m0) * CIN;
    for (int i = tid; i < rows * CIN; i += 256) xs[i] = xsrc[i];
    __syncthreads();

    int m = m0 + tid;
    float a1[16];
    #pragma unroll
    for (int i = 0; i < 16; ++i) a1[i] = 0.f;

    if (m < NN) {
        float a0[16];
        #pragma unroll
        for (int i = 0; i < 16; ++i) a0[i] = 0.f;
        for (int c = 0; c < CIN; ++c) {
            float xa = xs[tid * CIN + c];
            #pragma unroll
            for (int kd = 0; kd < 8; ++kd) {
                const float4 w = *(const float4*)&wl[(kd * CIN + c) * 4];
                const int d4 = (kd & 3) * 4;
                if (kd < 4) {
                    a0[d4+0] += xa*w.x; a0[d4+1] += xa*w.y;
                    a0[d4+2] += xa*w.z; a0[d4+3] += xa*w.w;
                } else {
                    a1[d4+0] += xa*w.x; a1[d4+1] += xa*w.y;
                    a1[d4+2] += xa*w.z; a1[d4+3] += xa*w.w;
                }
            }
        }
        // fold E-contraction for k=0 term: p0[j] = sum_d E[m,d]*a0[d*4+j]
        float4 em4 = ((const float4*)e)[m];
        float p0[4];
        #pragma unroll
        for (int j = 0; j < 4; ++j)
            p0[j] = em4.x*a0[j] + em4.y*a0[4+j] + em4.z*a0[8+j] + em4.w*a0[12+j];
        ((float4*)g0c)[(size_t)b * NN + m] = make_float4(p0[0], p0[1], p0[2], p0[3]);
    }

    // stage a1 -> LDS [m_local][dj] (stride 17)
    #pragma unroll
    for (int dj = 0; dj < 16; ++dj) ls[tid * 17 + dj] = f2bf(a1[dj]);
    __syncthreads();

    // coalesced write-out: wave w handles local chunks {2w, 2w+1}
    const int wave = tid >> 6, lane = tid & 63;
    const int qo = lane >> 4, dj = lane & 15;
    #pragma unroll
    for (int i = 0; i < 2; ++i) {
        const int lc = wave * 2 + i;
        const int ck = blockIdx.x * 8 + lc;
        short8 v;
        #pragma unroll
        for (int u = 0; u < 8; ++u)
            v[u] = (short)ls[(lc * 32 + qo * 8 + u) * 17 + dj];
        *(short8*)&gtf[((size_t)(ck * 16 + b)) * 512 + lane * 8] = v;
    }
}

// ---------------------------------------------------------------------------
// Kernel B (fused score-gen + fragment GEMM, explicit prefetch pipeline):
//   PG contribution over slice s: sum_m exp(relu(E_n.E_m)) * G1[m][col]
//   rsums[s][n] = per-slice row sum of scores (no atomics)
// Wave: row-tile rt = bx*4+wave (16 rows), all 16 col-tiles, 16 k-chunks.
// - Slice's E rows (512 x float4 = 8KB) staged in LDS once (1 barrier total).
// - afrag(st+1) scores computed (LDS broadcast reads + VALU) while st MFMAs.
// - bf[16] rotating register prefetch: B-frags for st+1 load during st.
// ---------------------------------------------------------------------------
template <bool CHECK>
static __device__ inline void kb_score8(const float4* __restrict__ esl,
                                        const float4 en, int k0m, int stq,
                                        float& rowsum, short8& af) {
    #pragma unroll
    for (int u = 0; u < 8; ++u) {
        float4 em = esl[stq + u];                  // broadcast within quad
        float dt = en.x*em.x + en.y*em.y + en.z*em.z + en.w*em.w;
        float sv = __expf(fmaxf(dt, 0.f));
        if (CHECK && (k0m + stq + u >= NN)) sv = 0.f;
        rowsum += sv;
        af[u] = (short)f2bf(sv);
    }
}

template <bool CHECK>
static __device__ inline void kb_main(const float4* __restrict__ esl,
                                      const ushort* __restrict__ gl,
                                      const float4 en, int k0m, int quad,
                                      floatx4 (&acc)[16], float& rowsum) {
    short8 af, afn;
    short8 bf[16];
    kb_score8<CHECK>(esl, en, k0m, quad * 8, rowsum, af);
    #pragma unroll
    for (int ct = 0; ct < 16; ++ct)
        bf[ct] = *(const short8*)&gl[ct * 512];

    #pragma unroll 4
    for (int st = 0; st < CPS; ++st) {
        const int stn = (st + 1 < CPS) ? st + 1 : st;
        // next scores (independent chain, overlaps MFMAs below)
        kb_score8<CHECK>(esl, en, k0m, stn * 32 + quad * 8, rowsum, afn);
        if (st + 1 == CPS) {  // avoid double-counting the redundant last pass
            #pragma unroll
            for (int u = 0; u < 8; ++u) {
                float4 em = esl[stn * 32 + quad * 8 + u];
                float dt = en.x*em.x + en.y*em.y + en.z*em.z + en.w*em.w;
                float sv = __expf(fmaxf(dt, 0.f));
                if (CHECK && (k0m + stn * 32 + quad * 8 + u >= NN)) sv = 0.f;
                rowsum -= sv;
            }
        }
        const ushort* gn = gl + (size_t)stn * 8192;
        #pragma unroll
        for (int ct = 0; ct < 16; ++ct) {
            acc[ct] = __builtin_amdgcn_mfma_f32_16x16x32_bf16(af, bf[ct], acc[ct], 0, 0, 0);
            bf[ct] = *(const short8*)&gn[ct * 512];
        }
        af = afn;
    }
}

__global__ __launch_bounds__(256, 3)
void kb_pg(const float* __restrict__ e, const ushort* __restrict__ gtf,
           float* __restrict__ pgp, float* __restrict__ rsums) {
    __shared__ float4 esl[512];          // slice's E rows, 8 KB
    const int tid  = threadIdx.x;
    const int wave = tid >> 6;
    const int lane = tid & 63;
    const int l15  = lane & 15;
    const int quad = lane >> 4;
    const int rt   = blockIdx.x * 4 + wave;
    const int s    = blockIdx.y;
    const int k0m  = s * (CPS * 32);     // first m of slice
    const float4* E4 = (const float4*)e;

    for (int i = tid; i < 512; i += 256) {
        int m = k0m + i;
        esl[i] = (m < NN) ? E4[m] : make_float4(0.f, 0.f, 0.f, 0.f);
    }
    const int nr = rt * 16 + l15;
    const float4 en = E4[nr < NN ? nr : 0];
    __syncthreads();

    floatx4 acc[16];
    #pragma unroll
    for (int i = 0; i < 16; ++i) acc[i] = (floatx4){0.f, 0.f, 0.f, 0.f};
    float rowsum = 0.f;

    const ushort* gl = gtf + (size_t)s * CPS * 8192 + lane * 8;

    if (k0m + CPS * 32 <= NN) kb_main<false>(esl, gl, en, k0m, quad, acc, rowsum);
    else                      kb_main<true >(esl, gl, en, k0m, quad, acc, rowsum);

    // rsums: row l15, partial per quad -> butterfly over quads, quad0 stores
    rowsum += __shfl_xor(rowsum, 16);
    rowsum += __shfl_xor(rowsum, 32);
    if (quad == 0) rsums[(size_t)s * MPAD + nr] = rowsum;   // nr < MPAD always

    // epilogue: acc[ct][j] = D[n = rt*16+quad*4+j][dj = l15]
    // contract dj = d*4+jj with E[n,d]: reduce over d via shfl_xor(4),(8)
    const int dsel = l15 >> 2, jj = l15 & 3;
    float end[4];
    #pragma unroll
    for (int j = 0; j < 4; ++j) {
        int n = rt * 16 + quad * 4 + j;
        end[j] = (n < NN) ? e[n * 4 + dsel] : 0.f;
    }
    #pragma unroll
    for (int ct = 0; ct < 16; ++ct) {
        #pragma unroll
        for (int j = 0; j < 4; ++j) {
            float v = end[j] * acc[ct][j];
            v += __shfl_xor(v, 4);
            v += __shfl_xor(v, 8);
            int n = rt * 16 + quad * 4 + j;
            if (l15 < 4 && n < NN)
                pgp[(((size_t)s * BB + ct) * NN + n) * 4 + jj] = v;
        }
    }
}

// ---------------------------------------------------------------------------
// Kernel E: tiny epilogue
// pre[j] = g0c[b][n][j] + (1/sum_s rsums[s][n]) * sum_s pgp[s][b][n][j]
//          + sum_d E[n,d]*bias[d][j]
// R=sigmoid(pre[0..1]), C=tanh(pre[2..3]), h=(1-R)*C, y = relu(h)@lin_w + lin_b
// ---------------------------------------------------------------------------
static __device__ inline float fsig(float x) {
    return 1.f / (1.f + __expf(-x));
}
static __device__ inline float ftanh(float x) {
    float t = __expf(fminf(2.f * x, 80.f));
    return (t - 1.f) / (t + 1.f);
}

__global__ __launch_bounds__(256)
void ke_out(const float* __restrict__ e, const float* __restrict__ rsums,
            const float* __restrict__ g0c, const float* __restrict__ pgp,
            const float* __restrict__ bg, const float* __restrict__ bu,
            const float* __restrict__ lw, const float* __restrict__ lb,
            float* __restrict__ out) {
    int n = blockIdx.x * 256 + threadIdx.x;
    int b = blockIdx.y;
    if (n >= NN) return;
    float4 ev = ((const float4*)e)[n];
    float ed[4] = {ev.x, ev.y, ev.z, ev.w};
    float den = 0.f;
    #pragma unroll
    for (int s = 0; s < OUTER; ++s) den += rsums[(size_t)s * MPAD + n];
    float rd = 1.f / den;

    float pgf[4] = {0.f, 0.f, 0.f, 0.f};
    #pragma unroll
    for (int s = 0; s < OUTER; ++s) {
        float4 t = ((const float4*)pgp)[((size_t)s * BB + b) * NN + n];
        pgf[0] += t.x; pgf[1] += t.y; pgf[2] += t.z; pgf[3] += t.w;
    }
    float4 g0v = ((const float4*)g0c)[(size_t)b * NN + n];
    float g0f[4] = {g0v.x, g0v.y, g0v.z, g0v.w};

    float pre[4];
    #pragma unroll
    for (int j = 0; j < 4; ++j) {
        float bj = 0.f;
        #pragma unroll
        for (int d = 0; d < 4; ++d) {
            float bp = (j < 2) ? bg[d * 4 + 2 + j] : bu[d * 2 + (j - 2)];
            bj += ed[d] * bp;
        }
        pre[j] = g0f[j] + rd * pgf[j] + bj;
    }
    float R0 = fsig(pre[0]);
    float R1 = fsig(pre[1]);
    float C0 = ftanh(pre[2]);
    float C1 = ftanh(pre[3]);
    float h0 = (1.f - R0) * C0;
    float h1 = (1.f - R1) * C1;
    float y = fmaxf(h0, 0.f) * lw[0] + fmaxf(h1, 0.f) * lw[1] + lb[0];
    out[(size_t)b * NN + n] = y;
}

// ---------------------------------------------------------------------------
extern "C" void kernel_launch(void* const* d_in, const int* in_sizes, int n_in,
                              void* d_out, int out_size, void* d_ws, size_t ws_size,
                              hipStream_t stream) {
    const float* x  = (const float*)d_in[0];
    const float* e  = (const float*)d_in[1];
    const float* wg = (const float*)d_in[2];
    const float* bg = (const float*)d_in[3];
    const float* wu = (const float*)d_in[4];
    const float* bu = (const float*)d_in[5];
    const float* lw = (const float*)d_in[6];
    const float* lb = (const float*)d_in[7];
    float* out = (float*)d_out;

    float*  wsf   = (float*)d_ws;
    float*  rsums = wsf + OFF_RSUM;
    float*  g0c   = wsf + OFF_G0C;
    float*  pgp   = wsf + OFF_PGP;
    ushort* gtf   = (ushort*)(wsf + OFF_GTF);

    hipLaunchKernelGGL(kg_g, dim3(22, 16), dim3(256), 0, stream, x, e, wg, wu, g0c, gtf);
    hipLaunchKernelGGL(kb_pg, dim3(88, OUTER), dim3(256), 0, stream, e, gtf, pgp, rsums);
    hipLaunchKernelGGL(ke_out, dim3(22, 16), dim3(256), 0, stream,
                       e, rsums, g0c, pgp, bg, bu, lw, lb, out);
}

// Round 8
// 120.904 us; speedup vs baseline: 2.1858x; 1.3567x over previous
//
#include <hip/hip_runtime.h>
#include <hip/hip_bf16.h>
#include <math.h>

// Problem constants (fixed by setup_inputs)
#define NN   5570
#define BB   16
#define CIN  35
#define MPAD 5632      // NN padded to 88*64
#define NCHUNK 176     // MPAD/32  (k-chunks of 32)
#define OUTER 11       // split-K slices (blockIdx.y); 16 chunks = 512 k each
#define CPS  16        // chunks per slice

// workspace layout (float offsets); total 5,060,608 floats ~= 20.2 MB
#define OFF_RSUM 0                          // [OUTER][MPAD] fp32 = 61952
#define OFF_G0C  61952                      // [BB][NN][4] fp32 = 356480
#define OFF_PGP  418432                     // [OUTER][BB][NN][4] fp32 = 3921280
#define OFF_GTF  4339712                    // gtf bf16 [NCHUNK][BB][64][8]

typedef __attribute__((ext_vector_type(8))) short  short8;
typedef __attribute__((ext_vector_type(4))) float  floatx4;

static __device__ inline ushort f2bf(float f) {
    union { __hip_bfloat16 h; ushort u; } cv;
    cv.h = __float2bfloat16(f);
    return cv.u;
}

// ---------------------------------------------------------------------------
// Kernel G: per (b, m):
//   a0[dj] = sum_c x[b,m,c]*w_k0[d,c,j];  g0c[b][m][j] = sum_d E[m,d]*a0[dj]
//   a1[dj] = sum_c x[b,m,c]*w_k1[d,c,j] -> gtf bf16 in MFMA-B-fragment order:
//       gtf[((ck*16 + b)*64 + quad*16 + dj)*8 + u],  m = ck*32 + quad*8 + u
// Writes go through an LDS transpose so global stores are coalesced short8.
// ---------------------------------------------------------------------------
__global__ __launch_bounds__(256)
void kg_g(const float* __restrict__ x, const float* __restrict__ e,
          const float* __restrict__ wg, const float* __restrict__ wu,
          float* __restrict__ g0c, ushort* __restrict__ gtf) {
    __shared__ float xs[256 * CIN];
    __shared__ float wl[8 * CIN * 4];    // [(k*4+d)*35 + c]*4 + j
    __shared__ ushort ls[256 * 17];      // staged a1, row stride 17 (pad)
    int tid = threadIdx.x;
    int b   = blockIdx.y;
    int m0  = blockIdx.x * 256;

    for (int i = tid; i < 8 * CIN * 4; i += 256) {
        int j = i & 3, rest = i >> 2;
        int c = rest % CIN, kd = rest / CIN;
        int k = kd >> 2, d = kd & 3;
        float v;
        if (j < 2) v = wg[((d * 2 + k) * 37 + c) * 4 + 2 + j];
        else       v = wu[((d * 2 + k) * 37 + c) * 2 + (j - 2)];
        wl[i] = v;
    }
    int rows = NN - m0; if (rows > 256) rows = 256; if (rows < 0) rows = 0;
    const float* xsrc = x + ((size_t)b * NN + m0) * CIN;
    for (int i = tid; i < rows * CIN; i += 256) xs[i] = xsrc[i];
    __syncthreads();

    int m = m0 + tid;
    float a1[16];
    #pragma unroll
    for (int i = 0; i < 16; ++i) a1[i] = 0.f;

    if (m < NN) {
        float a0[16];
        #pragma unroll
        for (int i = 0; i < 16; ++i) a0[i] = 0.f;
        for (int c = 0; c < CIN; ++c) {
            float xa = xs[tid * CIN + c];
            #pragma unroll
            for (int kd = 0; kd < 8; ++kd) {
                const float4 w = *(const float4*)&wl[(kd * CIN + c) * 4];
                const int d4 = (kd & 3) * 4;
                if (kd < 4) {
                    a0[d4+0] += xa*w.x; a0[d4+1] += xa*w.y;
                    a0[d4+2] += xa*w.z; a0[d4+3] += xa*w.w;
                } else {
                    a1[d4+0] += xa*w.x; a1[d4+1] += xa*w.y;
                    a1[d4+2] += xa*w.z; a1[d4+3] += xa*w.w;
                }
            }
        }
        // fold E-contraction for k=0 term: p0[j] = sum_d E[m,d]*a0[d*4+j]
        float4 em4 = ((const float4*)e)[m];
        float p0[4];
        #pragma unroll
        for (int j = 0; j < 4; ++j)
            p0[j] = em4.x*a0[j] + em4.y*a0[4+j] + em4.z*a0[8+j] + em4.w*a0[12+j];
        ((float4*)g0c)[(size_t)b * NN + m] = make_float4(p0[0], p0[1], p0[2], p0[3]);
    }

    // stage a1 -> LDS [m_local][dj] (stride 17)
    #pragma unroll
    for (int dj = 0; dj < 16; ++dj) ls[tid * 17 + dj] = f2bf(a1[dj]);
    __syncthreads();

    // coalesced write-out: wave w handles local chunks {2w, 2w+1}
    const int wave = tid >> 6, lane = tid & 63;
    const int qo = lane >> 4, dj = lane & 15;
    #pragma unroll
    for (int i = 0; i < 2; ++i) {
        const int lc = wave * 2 + i;
        const int ck = blockIdx.x * 8 + lc;
        short8 v;
        #pragma unroll
        for (int u = 0; u < 8; ++u)
            v[u] = (short)ls[(lc * 32 + qo * 8 + u) * 17 + dj];
        *(short8*)&gtf[((size_t)(ck * 16 + b)) * 512 + lane * 8] = v;
    }
}

// ---------------------------------------------------------------------------
// Kernel B (fused score-gen + MFMA, LDS double-buffered B via global_load_lds):
//   PG contribution over slice s: sum_m exp(relu(E_n.E_m)) * G1[m][col]
//   rsums[s][n] = per-slice row sum of scores (no atomics)
// Block = 4 waves; wave w owns row-tile rt = bx*4+w, all 16 col-tiles.
// Per step (32 k): prefetch next 16KB B-chunk into LDS (async DMA, issued
// right after the barrier so it overlaps this step's compute), compute 8
// scores/lane into the A-frag, 16 ds_read_b128 B-frags, 16 MFMA.
// All 4 waves share the staged chunk -> 4x VMEM reduction vs per-wave loads.
// ---------------------------------------------------------------------------
static __device__ inline void load_chunk(const ushort* __restrict__ gsrc,
                                         ushort* ldst, int tid, int wave) {
    #pragma unroll
    for (int i = 0; i < 4; ++i) {
        const ushort* g = gsrc + (size_t)(i * 256 + tid) * 8;
        ushort* l = ldst + (size_t)(i * 256 + wave * 64) * 8;  // wave-uniform base
        __builtin_amdgcn_global_load_lds(
            (const __attribute__((address_space(1))) unsigned int*)g,
            (__attribute__((address_space(3))) unsigned int*)l, 16, 0, 0);
    }
}

template <bool CHECK>
__device__ __forceinline__ void kb_main(const float4* __restrict__ esl,
                                        const ushort* __restrict__ gsl,
                                        ushort (*sbuf)[8192],
                                        const float4 en, int k0m,
                                        int tid, int wave, int lane, int quad,
                                        floatx4 (&acc)[16], float& rowsum) {
    #pragma unroll 2
    for (int st = 0; st < CPS; ++st) {
        __syncthreads();   // chunk st resident; all reads of buf[st&1]'s prior life done
        if (st + 1 < CPS)
            load_chunk(gsl + (size_t)(st + 1) * 8192, sbuf[(st + 1) & 1], tid, wave);

        // scores for this step's A-fragment: lane holds A[rt*16+l15][quad*8+u]
        short8 af;
        const int stq = st * 32 + quad * 8;
        #pragma unroll
        for (int u = 0; u < 8; ++u) {
            float4 em = esl[stq + u];
            float dt = en.x*em.x + en.y*em.y + en.z*em.z + en.w*em.w;
            float sv = __expf(fmaxf(dt, 0.f));
            if (CHECK && (k0m + stq + u >= NN)) sv = 0.f;
            rowsum += sv;
            af[u] = (short)f2bf(sv);
        }

        const ushort* bb = &sbuf[st & 1][lane * 8];
        #pragma unroll
        for (int ct = 0; ct < 16; ++ct) {
            short8 bf = *(const short8*)&bb[ct * 512];
            acc[ct] = __builtin_amdgcn_mfma_f32_16x16x32_bf16(af, bf, acc[ct], 0, 0, 0);
        }
    }
}

__global__ __launch_bounds__(256, 4)
void kb_pg(const float* __restrict__ e, const ushort* __restrict__ gtf,
           float* __restrict__ pgp, float* __restrict__ rsums) {
    __shared__ ushort sbuf[2][8192];     // double-buffered B chunk, 32 KB
    __shared__ float4 esl[512];          // slice's E rows, 8 KB
    const int tid  = threadIdx.x;
    const int wave = tid >> 6;
    const int lane = tid & 63;
    const int l15  = lane & 15;
    const int quad = lane >> 4;
    const int rt   = blockIdx.x * 4 + wave;
    const int s    = blockIdx.y;
    const int k0m  = s * (CPS * 32);     // first m of slice
    const float4* E4 = (const float4*)e;

    // stage slice E rows + first B chunk
    for (int i = tid; i < 512; i += 256) {
        int m = k0m + i;
        esl[i] = (m < NN) ? E4[m] : make_float4(0.f, 0.f, 0.f, 0.f);
    }
    const ushort* gsl = gtf + (size_t)s * CPS * 8192;
    load_chunk(gsl, sbuf[0], tid, wave);

    const int nr = rt * 16 + l15;
    const float4 en = E4[nr < NN ? nr : 0];

    floatx4 acc[16];
    #pragma unroll
    for (int i = 0; i < 16; ++i) acc[i] = (floatx4){0.f, 0.f, 0.f, 0.f};
    float rowsum = 0.f;

    if (k0m + CPS * 32 <= NN)
        kb_main<false>(esl, gsl, sbuf, en, k0m, tid, wave, lane, quad, acc, rowsum);
    else
        kb_main<true >(esl, gsl, sbuf, en, k0m, tid, wave, lane, quad, acc, rowsum);

    // rsums: row l15, partial per quad -> butterfly over quads, quad0 stores
    rowsum += __shfl_xor(rowsum, 16);
    rowsum += __shfl_xor(rowsum, 32);
    if (quad == 0) rsums[(size_t)s * MPAD + nr] = rowsum;   // nr < MPAD always

    // epilogue: acc[ct][j] = D[n = rt*16+quad*4+j][dj = l15]
    // contract dj = d*4+jj with E[n,d]: reduce over d via shfl_xor(4),(8)
    const int dsel = l15 >> 2, jj = l15 & 3;
    float end[4];
    #pragma unroll
    for (int j = 0; j < 4; ++j) {
        int n = rt * 16 + quad * 4 + j;
        end[j] = (n < NN) ? e[n * 4 + dsel] : 0.f;
    }
    #pragma unroll
    for (int ct = 0; ct < 16; ++ct) {
        #pragma unroll
        for (int j = 0; j < 4; ++j) {
            float v = end[j] * acc[ct][j];
            v += __shfl_xor(v, 4);
            v += __shfl_xor(v, 8);
            int n = rt * 16 + quad * 4 + j;
            if (l15 < 4 && n < NN)
                pgp[(((size_t)s * BB + ct) * NN + n) * 4 + jj] = v;
        }
    }
}

// ---------------------------------------------------------------------------
// Kernel E: tiny epilogue
// pre[j] = g0c[b][n][j] + (1/sum_s rsums[s][n]) * sum_s pgp[s][b][n][j]
//          + sum_d E[n,d]*bias[d][j]
// R=sigmoid(pre[0..1]), C=tanh(pre[2..3]), h=(1-R)*C, y = relu(h)@lin_w + lin_b
// ---------------------------------------------------------------------------
static __device__ inline float fsig(float x) {
    return 1.f / (1.f + __expf(-x));
}
static __device__ inline float ftanh(float x) {
    float t = __expf(fminf(2.f * x, 80.f));
    return (t - 1.f) / (t + 1.f);
}

__global__ __launch_bounds__(256)
void ke_out(const float* __restrict__ e, const float* __restrict__ rsums,
            const float* __restrict__ g0c, const float* __restrict__ pgp,
            const float* __restrict__ bg, const float* __restrict__ bu,
            const float* __restrict__ lw, const float* __restrict__ lb,
            float* __restrict__ out) {
    int n = blockIdx.x * 256 + threadIdx.x;
    int b = blockIdx.y;
    if (n >= NN) return;
    float4 ev = ((const float4*)e)[n];
    float ed[4] = {ev.x, ev.y, ev.z, ev.w};
    float den = 0.f;
    #pragma unroll
    for (int s = 0; s < OUTER; ++s) den += rsums[(size_t)s * MPAD + n];
    float rd = 1.f / den;

    float pgf[4] = {0.f, 0.f, 0.f, 0.f};
    #pragma unroll
    for (int s = 0; s < OUTER; ++s) {
        float4 t = ((const float4*)pgp)[((size_t)s * BB + b) * NN + n];
        pgf[0] += t.x; pgf[1] += t.y; pgf[2] += t.z; pgf[3] += t.w;
    }
    float4 g0v = ((const float4*)g0c)[(size_t)b * NN + n];
    float g0f[4] = {g0v.x, g0v.y, g0v.z, g0v.w};

    float pre[4];
    #pragma unroll
    for (int j = 0; j < 4; ++j) {
        float bj = 0.f;
        #pragma unroll
        for (int d = 0; d < 4; ++d) {
            float bp = (j < 2) ? bg[d * 4 + 2 + j] : bu[d * 2 + (j - 2)];
            bj += ed[d] * bp;
        }
        pre[j] = g0f[j] + rd * pgf[j] + bj;
    }
    float R0 = fsig(pre[0]);
    float R1 = fsig(pre[1]);
    float C0 = ftanh(pre[2]);
    float C1 = ftanh(pre[3]);
    float h0 = (1.f - R0) * C0;
    float h1 = (1.f - R1) * C1;
    float y = fmaxf(h0, 0.f) * lw[0] + fmaxf(h1, 0.f) * lw[1] + lb[0];
    out[(size_t)b * NN + n] = y;
}

// ---------------------------------------------------------------------------
extern "C" void kernel_launch(void* const* d_in, const int* in_sizes, int n_in,
                              void* d_out, int out_size, void* d_ws, size_t ws_size,
                              hipStream_t stream) {
    const float* x  = (const float*)d_in[0];
    const float* e  = (const float*)d_in[1];
    const float* wg = (const float*)d_in[2];
    const float* bg = (const float*)d_in[3];
    const float* wu = (const float*)d_in[4];
    const float* bu = (const float*)d_in[5];
    const float* lw = (const float*)d_in[6];
    const float* lb = (const float*)d_in[7];
    float* out = (float*)d_out;

    float*  wsf   = (float*)d_ws;
    float*  rsums = wsf + OFF_RSUM;
    float*  g0c   = wsf + OFF_G0C;
    float*  pgp   = wsf + OFF_PGP;
    ushort* gtf   = (ushort*)(wsf + OFF_GTF);

    hipLaunchKernelGGL(kg_g, dim3(22, 16), dim3(256), 0, stream, x, e, wg, wu, g0c, gtf);
    hipLaunchKernelGGL(kb_pg, dim3(88, OUTER), dim3(256), 0, stream, e, gtf, pgp, rsums);
    hipLaunchKernelGGL(ke_out, dim3(22, 16), dim3(256), 0, stream,
                       e, rsums, g0c, pgp, bg, bu, lw, lb, out);
}